// Round 1
// baseline (361.143 us; speedup 1.0000x reference)
//
#include <hip/hip_runtime.h>

// Problem constants (from reference)
#define BATCH   16
#define NTGT    50
#define NCLS    80
#define GRIDN   80          // H = W = 80
#define NANCH   3
#define PLANE   (GRIDN*GRIDN)        // 6400
#define CHTOT   (NANCH*(5+NCLS))     // 255

// scaled anchors = ANCHORS / (640/80) = ANCHORS / 8
__device__ __constant__ float c_aw[3] = {116.0f/8.0f, 156.0f/8.0f, 373.0f/8.0f}; // 14.5, 19.5, 46.625
__device__ __constant__ float c_ah[3] = { 90.0f/8.0f, 198.0f/8.0f, 326.0f/8.0f}; // 11.25, 24.75, 40.75

__device__ __forceinline__ float softplusf(float x) {
    // stable: max(x,0) + log1p(exp(-|x|))  (matches jax.nn.softplus numerics closely)
    return fmaxf(x, 0.0f) + log1pf(expf(-fabsf(x)));
}
__device__ __forceinline__ float sigmoidf_(float x) {
    return 1.0f / (1.0f + expf(-x));
}

// block-wide double reduction; result valid on thread 0
__device__ __forceinline__ double blockReduceD(double v) {
    for (int o = 32; o > 0; o >>= 1) v += __shfl_down(v, o, 64);
    __shared__ double smem[16];
    int lane = threadIdx.x & 63, wid = threadIdx.x >> 6;
    if (lane == 0) smem[wid] = v;
    __syncthreads();
    double r = 0.0;
    if (threadIdx.x == 0) {
        int nw = (blockDim.x + 63) >> 6;
        for (int i = 0; i < nw; i++) r += smem[i];
    }
    return r;
}

// ---------------------------------------------------------------------------
// Kernel 1: per-batch target assignment + dedup + obj-cell loss contributions.
// One block per batch image. All contributions pre-weighted, atomicAdd(double).
// ---------------------------------------------------------------------------
__global__ void ktargets(const float* __restrict__ pred,
                         const float* __restrict__ targets,
                         double* __restrict__ acc) {
    const int b   = blockIdx.x;
    const int tid = threadIdx.x;

    __shared__ int   s_key[NTGT];     // bestn*6400 + gj*80 + gi
    __shared__ int   s_valid[NTGT];
    __shared__ int   s_win[NTGT];     // unique obj cell, last-write-wins owner
    __shared__ int   s_cls[NTGT];
    __shared__ float s_gx[NTGT], s_gy[NTGT], s_gw[NTGT], s_gh[NTGT];
    __shared__ unsigned long long s_mlo[NTGT];  // class-union bits 0..63
    __shared__ unsigned int      s_mhi[NTGT];   // class-union bits 64..79

    if (tid < NTGT) {
        const float* t5 = targets + ((size_t)b * NTGT + tid) * 5;
        float cls = t5[0], x = t5[1], y = t5[2], w = t5[3], h = t5[4];
        float ssum = cls + x + y + w + h;
        float gx = x * (float)GRIDN, gy = y * (float)GRIDN;
        float gw = w * (float)GRIDN, gh = h * (float)GRIDN;
        int gi = (int)gx, gj = (int)gy;   // trunc, matches astype(int32) for positive vals
        int valid = (ssum != 0.0f) && (gi < GRIDN) && (gj < GRIDN);
        // best anchor (argmax -> first max wins ties)
        float best = -1.0f; int bestn = 0;
        #pragma unroll
        for (int a = 0; a < NANCH; a++) {
            float inter = fminf(gw, c_aw[a]) * fminf(gh, c_ah[a]);
            float iou   = inter / (gw * gh + c_aw[a] * c_ah[a] - inter + 1e-6f);
            if (iou > best) { best = iou; bestn = a; }
        }
        s_key[tid]   = bestn * PLANE + gj * GRIDN + gi;
        s_valid[tid] = valid;
        s_cls[tid]   = (int)cls;
        s_gx[tid] = gx; s_gy[tid] = gy; s_gw[tid] = gw; s_gh[tid] = gh;
    }
    __syncthreads();

    if (tid < NTGT) {
        // last-write-wins: I own the cell iff no LATER valid target hits same key
        int win = s_valid[tid];
        if (win) {
            for (int t2 = tid + 1; t2 < NTGT; t2++)
                if (s_valid[t2] && s_key[t2] == s_key[tid]) { win = 0; break; }
        }
        unsigned long long mlo = 0ull; unsigned int mhi = 0u;
        if (win) {
            // tcls is the UNION of class ids of all valid targets at this cell
            for (int t2 = 0; t2 < NTGT; t2++) {
                if (s_valid[t2] && s_key[t2] == s_key[tid]) {
                    int c = s_cls[t2];
                    if (c < 64) mlo |= 1ull << c; else mhi |= 1u << (c - 64);
                }
            }
        }
        s_win[tid] = win; s_mlo[tid] = mlo; s_mhi[tid] = mhi;
    }
    __syncthreads();

    const double w_coord = 5.0 / (double)BATCH;   // lambda_coord / B
    const double w_one   = 1.0 / (double)BATCH;
    const double w_noobj = 0.5 / (double)BATCH;   // lambda_noobj / B

    double local = 0.0;
    for (int t = 0; t < NTGT; t++) {
        if (!s_win[t]) continue;
        int key = s_key[t];
        int a   = key / PLANE;
        int rem = key % PLANE;               // gj*80 + gi
        size_t base = ((size_t)b * CHTOT + (size_t)a * (5 + NCLS)) * PLANE + rem;

        if (tid < NCLS) {
            // class BCE: softplus(z) - [c in set] * z
            float z = pred[base + (size_t)(5 + tid) * PLANE];
            bool inset = (tid < 64) ? ((s_mlo[t] >> tid) & 1ull)
                                    : ((s_mhi[t] >> (tid - 64)) & 1u);
            local += w_one * ((double)softplusf(z) - (inset ? (double)z : 0.0));
        } else if (tid == NCLS) {            // x
            float sx = sigmoidf_(pred[base]);
            float tx = s_gx[t] - (float)(rem % GRIDN);
            local += w_coord * ((double)softplusf(sx) - (double)tx * (double)sx);
        } else if (tid == NCLS + 1) {        // y
            float sy = sigmoidf_(pred[base + (size_t)PLANE]);
            float ty = s_gy[t] - (float)(rem / GRIDN);
            local += w_coord * ((double)softplusf(sy) - (double)ty * (double)sy);
        } else if (tid == NCLS + 2) {        // w (raw, squared error)
            float pw = pred[base + 2 * (size_t)PLANE];
            float tw = logf(s_gw[t] / c_aw[a] + 1e-16f);
            float d = pw - tw;
            local += w_coord * (double)d * (double)d;
        } else if (tid == NCLS + 3) {        // h
            float ph = pred[base + 3 * (size_t)PLANE];
            float th = logf(s_gh[t] / c_ah[a] + 1e-16f);
            float d = ph - th;
            local += w_coord * (double)d * (double)d;
        } else if (tid == NCLS + 4) {        // conf at obj cell
            float conf = sigmoidf_(pred[base + 4 * (size_t)PLANE]);
            float sp = softplusf(conf);
            // + BCE(conf,1) = softplus(conf)-conf ;  remove this cell from noobj sum
            local += w_one * ((double)sp - (double)conf) - w_noobj * (double)sp;
        }
    }

    double r = blockReduceD(local);
    if (tid == 0) atomicAdd(acc, r);
}

// ---------------------------------------------------------------------------
// Kernel 2: dense no-obj conf term over ALL cells (obj cells subtracted above).
// 16*3*6400 = 307200 conf logits = 1.2 MB read.
// ---------------------------------------------------------------------------
__global__ void knoobj(const float* __restrict__ pred, double* __restrict__ acc) {
    const double w_noobj = 0.5 / (double)BATCH;
    int idx = blockIdx.x * blockDim.x + threadIdx.x;
    double local = 0.0;
    const int total = BATCH * NANCH * PLANE;
    if (idx < total) {
        int b = idx / (NANCH * PLANE);
        int r = idx % (NANCH * PLANE);
        int a = r / PLANE;
        int s = r % PLANE;
        float v = pred[((size_t)b * CHTOT + (size_t)a * (5 + NCLS) + 4) * PLANE + s];
        local = w_noobj * (double)softplusf(sigmoidf_(v));
    }
    double r = blockReduceD(local);
    if (threadIdx.x == 0) atomicAdd(acc, r);
}

__global__ void kfinal(const double* __restrict__ acc, float* __restrict__ out) {
    out[0] = (float)acc[0];
}

extern "C" void kernel_launch(void* const* d_in, const int* in_sizes, int n_in,
                              void* d_out, int out_size, void* d_ws, size_t ws_size,
                              hipStream_t stream) {
    const float* pred    = (const float*)d_in[0];
    const float* targets = (const float*)d_in[1];
    float* out = (float*)d_out;
    double* acc = (double*)d_ws;

    // d_ws is re-poisoned to 0xAA before every timed launch -> must zero.
    hipMemsetAsync(acc, 0, sizeof(double), stream);

    ktargets<<<BATCH, 256, 0, stream>>>(pred, targets, acc);

    const int total = BATCH * NANCH * PLANE;          // 307200
    knoobj<<<(total + 255) / 256, 256, 0, stream>>>(pred, acc);

    kfinal<<<1, 1, 0, stream>>>(acc, out);
}

// Round 4
// 142.305 us; speedup vs baseline: 2.5378x; 2.5378x over previous
//
#include <hip/hip_runtime.h>

// Problem constants (from reference)
#define BATCH   16
#define NTGT    50
#define NCLS    80
#define GRIDN   80                  // H = W
#define NANCH   3
#define PLANE   (GRIDN*GRIDN)       // 6400
#define CHPA    (5+NCLS)            // 85
#define CHTOT   (NANCH*CHPA)        // 255

#define OBJ_BLOCKS   (BATCH*NTGT)   // 800 — one block per (batch, target)
#define NOOBJ_BLOCKS 96             // grid-stride float4 over 48 conf planes
#define TOTAL_BLOCKS (OBJ_BLOCKS + NOOBJ_BLOCKS)  // 896
#define BLOCKSZ      128

// scaled anchors = ANCHORS / (640/80) = ANCHORS / 8
__device__ __constant__ float c_aw[3] = {14.5f, 19.5f, 46.625f};
__device__ __constant__ float c_ah[3] = {11.25f, 24.75f, 40.75f};

__device__ __forceinline__ float softplusf(float x) {
    return fmaxf(x, 0.0f) + log1pf(expf(-fabsf(x)));
}
__device__ __forceinline__ float sigmoidf_(float x) {
    return 1.0f / (1.0f + expf(-x));
}

// ---------------------------------------------------------------------------
// One fused kernel:
//   blocks [0, 800):   obj path — block (b,t) recomputes per-batch target keys
//                      (targets are 16 KB total, L2-hot), dedups, and if target
//                      t owns its cell, 85 lanes gather the cell's channels in
//                      ONE parallel round (vs. round-1's serial 50-iter chain).
//   blocks [800, 896): noobj path — dense softplus(sigmoid(conf)) sum,
//                      contiguous float4 loads.
// Every block WRITES partial[blockIdx] (ws is poisoned 0xAA) — no memset node.
// ---------------------------------------------------------------------------
__global__ void kmain(const float* __restrict__ pred,
                      const float* __restrict__ targets,
                      double* __restrict__ partial) {
    const int blk = blockIdx.x;
    const int tid = threadIdx.x;

    const double w_coord = 5.0 / (double)BATCH;
    const double w_one   = 1.0 / (double)BATCH;
    const double w_noobj = 0.5 / (double)BATCH;

    __shared__ int   s_key[NTGT];
    __shared__ int   s_valid[NTGT];
    __shared__ int   s_cls[NTGT];
    __shared__ float s_g[4];          // gx,gy,gw,gh of THIS block's target
    __shared__ double s_red[2];

    double local = 0.0;

    if (blk < OBJ_BLOCKS) {
        const int b = blk / NTGT;
        const int t = blk % NTGT;

        if (tid < NTGT) {
            const float* t5 = targets + ((size_t)b * NTGT + tid) * 5;
            float c = t5[0], x = t5[1], y = t5[2], w = t5[3], h = t5[4];
            float ssum = c + x + y + w + h;
            float gx = x * (float)GRIDN, gy = y * (float)GRIDN;
            float gw = w * (float)GRIDN, gh = h * (float)GRIDN;
            int gi = (int)gx, gj = (int)gy;          // trunc == floor (positive)
            int valid = (ssum != 0.0f) && (gi < GRIDN) && (gj < GRIDN);
            float best = -1.0f; int bestn = 0;
            #pragma unroll
            for (int a = 0; a < NANCH; a++) {
                float inter = fminf(gw, c_aw[a]) * fminf(gh, c_ah[a]);
                float iou   = inter / (gw * gh + c_aw[a] * c_ah[a] - inter + 1e-6f);
                if (iou > best) { best = iou; bestn = a; }   // first-max wins, matches argmax
            }
            s_key[tid]   = bestn * PLANE + gj * GRIDN + gi;
            s_valid[tid] = valid;
            s_cls[tid]   = (int)c;
            if (tid == t) { s_g[0] = gx; s_g[1] = gy; s_g[2] = gw; s_g[3] = gh; }
        }
        __syncthreads();

        // last-write-wins ownership (uniform across block)
        const int mykey = s_key[t];
        bool win = (s_valid[t] != 0);
        if (win) {
            for (int t2 = t + 1; t2 < NTGT; t2++)
                if (s_valid[t2] && s_key[t2] == mykey) { win = false; break; }
        }
        if (!win) { if (tid == 0) partial[blk] = 0.0; return; }

        // tcls = UNION of class ids of all colliding valid targets
        unsigned long long mlo = 0ull; unsigned int mhi = 0u;
        for (int t2 = 0; t2 < NTGT; t2++) {
            if (s_valid[t2] && s_key[t2] == mykey) {
                int c = s_cls[t2];
                if (c < 64) mlo |= 1ull << c; else mhi |= 1u << (c - 64);
            }
        }

        const int a   = mykey / PLANE;
        const int rem = mykey % PLANE;               // gj*80 + gi
        const size_t base = ((size_t)b * CHTOT + (size_t)a * CHPA) * PLANE + rem;

        if (tid < NCLS) {
            // BCE(z,t) = softplus(z) - t*z
            float z = pred[base + (size_t)(5 + tid) * PLANE];
            bool inset = (tid < 64) ? ((mlo >> tid) & 1ull)
                                    : ((mhi >> (tid - 64)) & 1u);
            local = w_one * ((double)softplusf(z) - (inset ? (double)z : 0.0));
        } else if (tid == NCLS) {                    // x (BCE on sigmoid output)
            float sx = sigmoidf_(pred[base]);
            float tx = s_g[0] - (float)(rem % GRIDN);
            local = w_coord * ((double)softplusf(sx) - (double)tx * (double)sx);
        } else if (tid == NCLS + 1) {                // y
            float sy = sigmoidf_(pred[base + (size_t)PLANE]);
            float ty = s_g[1] - (float)(rem / GRIDN);
            local = w_coord * ((double)softplusf(sy) - (double)ty * (double)sy);
        } else if (tid == NCLS + 2) {                // w (squared error, raw)
            float pw = pred[base + 2 * (size_t)PLANE];
            float tw = logf(s_g[2] / c_aw[a] + 1e-16f);
            float d = pw - tw;
            local = w_coord * (double)d * (double)d;
        } else if (tid == NCLS + 3) {                // h
            float ph = pred[base + 3 * (size_t)PLANE];
            float th = logf(s_g[3] / c_ah[a] + 1e-16f);
            float d = ph - th;
            local = w_coord * (double)d * (double)d;
        } else if (tid == NCLS + 4) {                // conf at obj cell
            float conf = sigmoidf_(pred[base + 4 * (size_t)PLANE]);
            float sp = softplusf(conf);
            // BCE(conf,1)=softplus(conf)-conf ; also remove cell from dense noobj sum
            local = w_one * ((double)sp - (double)conf) - w_noobj * (double)sp;
        }
    } else {
        // dense no-obj conf term: 48 planes × 6400 floats, float4 grid-stride
        const int nb = blk - OBJ_BLOCKS;
        const int stride = NOOBJ_BLOCKS * BLOCKSZ;
        const int nvec = BATCH * NANCH * (PLANE / 4);          // 76800
        for (int i = nb * BLOCKSZ + tid; i < nvec; i += stride) {
            int ba = i / (PLANE / 4);
            int s4 = i % (PLANE / 4);
            int b = ba / NANCH, a = ba % NANCH;
            const float4* p4 = (const float4*)(pred + ((size_t)b * CHTOT + (size_t)a * CHPA + 4) * PLANE);
            float4 v = p4[s4];
            local += (double)(softplusf(sigmoidf_(v.x)) + softplusf(sigmoidf_(v.y))
                            + softplusf(sigmoidf_(v.z)) + softplusf(sigmoidf_(v.w)));
        }
        local *= w_noobj;
    }

    // block reduction (128 threads = 2 waves), write partial slot
    for (int o = 32; o > 0; o >>= 1) local += __shfl_down(local, o, 64);
    if ((tid & 63) == 0) s_red[tid >> 6] = local;
    __syncthreads();
    if (tid == 0) partial[blk] = s_red[0] + s_red[1];
}

__global__ void kfinal(const double* __restrict__ partial, float* __restrict__ out) {
    double v = 0.0;
    for (int i = threadIdx.x; i < TOTAL_BLOCKS; i += 256) v += partial[i];
    for (int o = 32; o > 0; o >>= 1) v += __shfl_down(v, o, 64);
    __shared__ double s[4];
    if ((threadIdx.x & 63) == 0) s[threadIdx.x >> 6] = v;
    __syncthreads();
    if (threadIdx.x == 0) out[0] = (float)(s[0] + s[1] + s[2] + s[3]);
}

extern "C" void kernel_launch(void* const* d_in, const int* in_sizes, int n_in,
                              void* d_out, int out_size, void* d_ws, size_t ws_size,
                              hipStream_t stream) {
    const float* pred    = (const float*)d_in[0];
    const float* targets = (const float*)d_in[1];
    float* out = (float*)d_out;
    double* partial = (double*)d_ws;   // TOTAL_BLOCKS doubles = 7168 B

    kmain<<<TOTAL_BLOCKS, BLOCKSZ, 0, stream>>>(pred, targets, partial);
    kfinal<<<1, 256, 0, stream>>>(partial, out);
}